// Round 20
// baseline (107.094 us; speedup 1.0000x reference)
//
#include <hip/hip_runtime.h>
#include <math.h>

// UnrolledMeanShift: B=2, D=32, H=W=256, K=5x5, 3 iterations.
// R20 = R15 (proven best, 31.3us: dot-expansion weight with S from LDS,
// packed-fp16 num, 2 thr/pixel + DPP pair-combine, vectorized staging)
// with two structural tweaks, NBODY untouched:
//  1) 32-wide x 16-tall tile, 1024-thread blocks: overstage 1.88x -> 1.56x,
//     grid = 256 blocks = exactly 1/CU (no tail), 16 waves/CU preserved,
//     launch_bounds(1024,1) -> 128-VGPR budget (2x R15's headroom).
//  2) full `#pragma unroll` on the di loop (S comes from LDS per NBODY, so
//     the live set stays ~55 regs -- unlike R12/R13's 25 named-S spill):
//     scheduler can hoist next-row ds_reads under current-row FMA chains.

typedef _Float16 h2  __attribute__((ext_vector_type(2)));
typedef unsigned int u4v __attribute__((ext_vector_type(4)));

constexpr int Dch  = 32;
constexpr int HH   = 256;
constexpr int WW   = 256;
constexpr int BH   = 16;              // tile rows
constexpr int BW   = 32;              // tile cols
constexpr int THs  = 20;              // staged rows (rel -2..17)
constexpr int NCOL = 40;              // staged cols (rel -4..35)
constexpr int RSTR = 41;              // staged row stride (40 + 1 pad)
constexpr int PSTR = THs * RSTR + 1;  // 821 words plane stride
constexpr int NJOB = 4 * THs * 10;    // 800 staging jobs
constexpr int ITERS = 3;
constexpr int HWp  = HH * WW;
constexpr int NTHR = 1024;            // 2 halves x 512 pixels

__device__ __forceinline__ float fdot2f(h2 a, h2 b, float c) {
    return __builtin_amdgcn_fdot2(a, b, c, false);
}

__device__ __forceinline__ float EXP2F(float x) {
#if __has_builtin(__builtin_amdgcn_exp2f)
    return __builtin_amdgcn_exp2f(x);
#else
    return __expf(x * 0.69314718055994531f);
#endif
}

// value from lane^1 (quad_perm [1,0,3,2]) — pure VALU, no LDS pipe
__device__ __forceinline__ float qswap(float x) {
#if __has_builtin(__builtin_amdgcn_mov_dpp)
    return __int_as_float(
        __builtin_amdgcn_mov_dpp(__float_as_int(x), 0xB1, 0xF, 0xF, true));
#else
    return __shfl_xor(x, 1, 64);
#endif
}

__device__ __forceinline__ h2 as_h2(unsigned int x) {
    return __builtin_bit_cast(h2, x);
}

// pack two f32 -> h2 with one v_cvt_pkrtz_f16_f32
__device__ __forceinline__ h2 pk2(float a, float b) {
#if __has_builtin(__builtin_amdgcn_cvt_pkrtz)
    return __builtin_bit_cast(h2, __builtin_amdgcn_cvt_pkrtz(a, b));
#else
    h2 r; r[0] = (_Float16)a; r[1] = (_Float16)b; return r;
#endif
}

__device__ __forceinline__ unsigned int pku(float a, float b) {
    return __builtin_bit_cast(unsigned int, pk2(a, b));
}

__global__ __launch_bounds__(NTHR, 1)
void meanshift_kernel(const float* __restrict__ E,
                      const float* __restrict__ lbw,
                      float* __restrict__ out)
{
    __shared__ u4v  tile[4 * PSTR];      // 52.5 KB (fp16, 8ch/16B word)
    __shared__ float sqv[THs * RSTR];    // -0.5*NC*|p|^2 (full 32 ch)

    const int bz  = blockIdx.z;
    const int oh  = blockIdx.y * BH - 2;       // staged row 0 = rel -2
    const int owc = blockIdx.x * BW;           // true tile col origin
    const int gw0 = owc - 4;                   // staged col 0 = rel -4
    const int tid = threadIdx.x;
    const int half = tid & 1;
    const int pix  = tid >> 1;                 // 0..511
    const int px   = pix & (BW - 1);           // 0..31
    const int py   = pix >> 5;                 // 0..15
    const int c0   = 2 * half;

    const float bwv = log1pf(__expf(lbw[0]));     // softplus
    const float cc2 = 1.0f / (2.0f * bwv * bwv);
    const float NCf = cc2 * 1.44269504f;          // w = 2^(-NC*dist^2)
    const float A2f = 2.0f * NCf;                 // coef on p.z
    const float MZC = -1.0f / (8.0f * NCf);       // mzz = MZC * |zs|^2_full

    const float* Eb = E + (size_t)bz * Dch * HWp;

    // ---- vectorized staging: 1 job/thread = 8ch x 4px ----
    if (tid < NJOB) {
        const int cc  = tid / (THs * 10);
        const int rem = tid - cc * (THs * 10);
        const int row = rem / 10;
        const int g   = rem - row * 10;
        const int gh  = oh + row;
        const int gwb = gw0 + 4 * g;

        float4 F0 = {0.f,0.f,0.f,0.f}, F1 = F0, F2 = F0, F3 = F0;
        float4 F4 = F0, F5 = F0, F6 = F0, F7 = F0;
        if ((unsigned)gh < (unsigned)HH) {
            const float* base = Eb + (size_t)(8 * cc) * HWp + gh * WW;
            if (gwb >= 0 && gwb + 4 <= WW) {      // aligned fast path
                F0 = *(const float4*)(base + 0 * (size_t)HWp + gwb);
                F1 = *(const float4*)(base + 1 * (size_t)HWp + gwb);
                F2 = *(const float4*)(base + 2 * (size_t)HWp + gwb);
                F3 = *(const float4*)(base + 3 * (size_t)HWp + gwb);
                F4 = *(const float4*)(base + 4 * (size_t)HWp + gwb);
                F5 = *(const float4*)(base + 5 * (size_t)HWp + gwb);
                F6 = *(const float4*)(base + 6 * (size_t)HWp + gwb);
                F7 = *(const float4*)(base + 7 * (size_t)HWp + gwb);
            } else {                               // edge: per-element
                const bool i0 = (unsigned)(gwb + 0) < (unsigned)WW;
                const bool i1 = (unsigned)(gwb + 1) < (unsigned)WW;
                const bool i2 = (unsigned)(gwb + 2) < (unsigned)WW;
                const bool i3 = (unsigned)(gwb + 3) < (unsigned)WW;
#define GE(K) F##K = make_float4( \
                    i0 ? base[(K) * (size_t)HWp + gwb + 0] : 0.f, \
                    i1 ? base[(K) * (size_t)HWp + gwb + 1] : 0.f, \
                    i2 ? base[(K) * (size_t)HWp + gwb + 2] : 0.f, \
                    i3 ? base[(K) * (size_t)HWp + gwb + 3] : 0.f)
                GE(0); GE(1); GE(2); GE(3); GE(4); GE(5); GE(6); GE(7);
#undef GE
            }
        }
        // register transpose: 4 pixels' 8-channel words
        const int wbase = cc * PSTR + row * RSTR + 4 * g;
        u4v W;
        W[0]=pku(F0.x,F1.x); W[1]=pku(F2.x,F3.x); W[2]=pku(F4.x,F5.x); W[3]=pku(F6.x,F7.x);
        tile[wbase + 0] = W;
        W[0]=pku(F0.y,F1.y); W[1]=pku(F2.y,F3.y); W[2]=pku(F4.y,F5.y); W[3]=pku(F6.y,F7.y);
        tile[wbase + 1] = W;
        W[0]=pku(F0.z,F1.z); W[1]=pku(F2.z,F3.z); W[2]=pku(F4.z,F5.z); W[3]=pku(F6.z,F7.z);
        tile[wbase + 2] = W;
        W[0]=pku(F0.w,F1.w); W[1]=pku(F2.w,F3.w); W[2]=pku(F4.w,F5.w); W[3]=pku(F6.w,F7.w);
        tile[wbase + 3] = W;
    }
    __syncthreads();

    // ---- precompute sqv = -0.5*NC*|p|^2 (all 32 ch), 1 pixel/thread ----
    if (tid < THs * NCOL) {
        const int row = tid / NCOL;
        const int col = tid - row * NCOL;
        const int p   = row * RSTR + col;
        const u4v t0 = tile[0 * PSTR + p], t1 = tile[1 * PSTR + p];
        const u4v t2 = tile[2 * PSTR + p], t3 = tile[3 * PSTR + p];
        float a0 = 0.f, a1 = 0.f, a2 = 0.f, a3 = 0.f;
        #pragma unroll
        for (int j = 0; j < 4; ++j) {
            const h2 q0 = as_h2(t0[j]); a0 = fdot2f(q0, q0, a0);
            const h2 q1 = as_h2(t1[j]); a1 = fdot2f(q1, q1, a1);
            const h2 q2 = as_h2(t2[j]); a2 = fdot2f(q2, q2, a2);
            const h2 q3 = as_h2(t3[j]); a3 = fdot2f(q3, q3, a3);
        }
        sqv[p] = -0.5f * NCf * ((a0 + a1) + (a2 + a3));
    }
    __syncthreads();

    const u4v* __restrict__ tA = tile + c0 * PSTR;
    const u4v* __restrict__ tB = tA + PSTR;

    // ---- init zs = A2 * z(own pixel), my 16 channels ----
    h2 zs0, zs1, zs2, zs3, zs4, zs5, zs6, zs7;
    {
        const int myp = (py + 2) * RSTR + (px + 4);   // window center
        const u4v ca = tA[myp];
        const u4v cb = tB[myp];
        const h2 A2v = pk2(A2f, A2f);
        zs0 = as_h2(ca[0]) * A2v; zs1 = as_h2(ca[1]) * A2v;
        zs2 = as_h2(ca[2]) * A2v; zs3 = as_h2(ca[3]) * A2v;
        zs4 = as_h2(cb[0]) * A2v; zs5 = as_h2(cb[1]) * A2v;
        zs6 = as_h2(cb[2]) * A2v; zs7 = as_h2(cb[3]) * A2v;
    }

    float* Ob = out + (size_t)bz * Dch * HWp;
    const int off    = (oh + 2 + py) * WW + (owc + px);
    const int chbase = 16 * half;

#define NBODY(NPI) do {                                                       \
        const u4v a  = tA[(NPI)];                                             \
        const u4v bq = tB[(NPI)];                                             \
        const float Sv = sqv[(NPI)];                                          \
        const h2 pa0 = as_h2(a[0]),  pa1 = as_h2(a[1]);                       \
        const h2 pa2 = as_h2(a[2]),  pa3 = as_h2(a[3]);                       \
        const h2 pb0 = as_h2(bq[0]), pb1 = as_h2(bq[1]);                      \
        const h2 pb2 = as_h2(bq[2]), pb3 = as_h2(bq[3]);                      \
        float s0 = fdot2f(pa0, zs0, Sv);                                      \
        s0 = fdot2f(pa1, zs1, s0); s0 = fdot2f(pa2, zs2, s0);                 \
        s0 = fdot2f(pa3, zs3, s0);                                            \
        float s1 = fdot2f(pb0, zs4, mzz);                                     \
        s1 = fdot2f(pb1, zs5, s1); s1 = fdot2f(pb2, zs6, s1);                 \
        s1 = fdot2f(pb3, zs7, s1);                                            \
        const float dp  = s0 + s1;                                            \
        const float arg = dp + qswap(dp);   /* A2 p.z - NC|p|^2 - NC|z|^2 */  \
        const float w   = EXP2F(arg);       /* <= ~1 */                       \
        den += w;                                                             \
        const h2 w2v = pk2(w, w);                                             \
        n0 += pa0 * w2v; n1 += pa1 * w2v; n2 += pa2 * w2v; n3 += pa3 * w2v;   \
        n4 += pb0 * w2v; n5 += pb1 * w2v; n6 += pb2 * w2v; n7 += pb3 * w2v;   \
    } while (0)

    #pragma unroll 1
    for (int it = 0; it < ITERS; ++it) {
        // mzz = -0.5*NC*|z|^2 (full 32 ch), from |zs|^2 = A2^2 |z|^2
        float mzz;
        {
            float q0 = fdot2f(zs0, zs0, 0.f);
            q0 = fdot2f(zs1, zs1, q0); q0 = fdot2f(zs2, zs2, q0);
            q0 = fdot2f(zs3, zs3, q0);
            float q1 = fdot2f(zs4, zs4, 0.f);
            q1 = fdot2f(zs5, zs5, q1); q1 = fdot2f(zs6, zs6, q1);
            q1 = fdot2f(zs7, zs7, q1);
            const float qs = q0 + q1;
            mzz = (qs + qswap(qs)) * MZC;
        }

        h2 n0 = {(_Float16)0.f, (_Float16)0.f};
        h2 n1 = n0, n2 = n0, n3 = n0, n4 = n0, n5 = n0, n6 = n0, n7 = n0;
        float den = 0.f;

        #pragma unroll
        for (int di = 0; di < 5; ++di) {
            const int rb = (py + di) * RSTR + px + 2;
            NBODY(rb + 0);
            NBODY(rb + 1);
            NBODY(rb + 2);
            NBODY(rb + 3);
            NBODY(rb + 4);
        }

        const float invf = 1.0f / (den + 1e-6f);
        if (it == ITERS - 1) {
#define WR(IDX, NV, EL) Ob[(size_t)(chbase + (IDX)) * HWp + off] = (float)NV[EL] * invf
            WR(0,  n0, 0); WR(1,  n0, 1); WR(2,  n1, 0); WR(3,  n1, 1);
            WR(4,  n2, 0); WR(5,  n2, 1); WR(6,  n3, 0); WR(7,  n3, 1);
            WR(8,  n4, 0); WR(9,  n4, 1); WR(10, n5, 0); WR(11, n5, 1);
            WR(12, n6, 0); WR(13, n6, 1); WR(14, n7, 0); WR(15, n7, 1);
#undef WR
        } else {
            // zs_new = A2 * (num * invf): fold A2 into the inverse
            const float ia = invf * A2f;
            const h2 iv = pk2(ia, ia);
            zs0 = n0 * iv; zs1 = n1 * iv; zs2 = n2 * iv; zs3 = n3 * iv;
            zs4 = n4 * iv; zs5 = n5 * iv; zs6 = n6 * iv; zs7 = n7 * iv;
        }
    }
#undef NBODY
}

extern "C" void kernel_launch(void* const* d_in, const int* in_sizes, int n_in,
                              void* d_out, int out_size, void* d_ws, size_t ws_size,
                              hipStream_t stream) {
    const float* E   = (const float*)d_in[0];
    const float* lbw = (const float*)d_in[1];
    float* out       = (float*)d_out;

    const int B = in_sizes[0] / (Dch * HWp);       // = 2
    dim3 grid(WW / BW, HH / BH, B);                // (8,16,2) = 256 blocks
    dim3 block(NTHR, 1, 1);                        // 1024 threads (2/pixel)
    hipLaunchKernelGGL(meanshift_kernel, grid, block, 0, stream, E, lbw, out);
}

// Round 22
// 31.144 us; speedup vs baseline: 3.4387x; 3.4387x over previous
//
#include <hip/hip_runtime.h>
#include <math.h>

// UnrolledMeanShift: B=2, D=32, H=W=256, K=5x5, 3 iterations.
// FINAL = R15 (best measured: 31.3us, 1.50x over round-1 baseline).
// (Round-21 submission of this identical source failed on an infra error —
//  UnresponsiveContainer — resubmitting unchanged.)
// Design (validated across 20 rounds):
//  - fp16 LDS halo tile, channel-planar 16B words (8ch/word), staged via
//    vectorized float4 x8 loads + register transpose (v_cvt_pkrtz).
//  - 2 threads/pixel (16 ch each); pair scalar combined with one DPP
//    quad_perm (no LDS for the reduction).
//  - weight exponent by dot-expansion: arg = A2*(p.z) - NC|p|^2 - NC|z|^2,
//    with -0.5NC|p|^2 precomputed per tile pixel in LDS (register-hoisting
//    it spills: R12/R13/R16/R18/R20), mzz once per iteration, zs = A2*z.
//  - packed-fp16 numerator (v_pk_fma_f16), w<=1 guaranteed by construction.
//  - all per-thread state is named SSA; no arrays (scratch lessons R4-R6).

typedef _Float16 h2  __attribute__((ext_vector_type(2)));
typedef unsigned int u4v __attribute__((ext_vector_type(4)));

constexpr int Dch  = 32;
constexpr int HH   = 256;
constexpr int WW   = 256;
constexpr int PADp = 2;
constexpr int BH   = 16;
constexpr int BW   = 16;
constexpr int THs  = 20;              // staged rows (rel -2..17)
constexpr int RSTR = 25;              // staged row stride: 24 cols + 1 pad
constexpr int PSTR = THs * RSTR + 1;  // 501 words plane stride
constexpr int NJOB = 4 * THs * 6;     // 480 staging jobs
constexpr int ITERS = 3;
constexpr int HWp  = HH * WW;
constexpr int NTHR = 512;

__device__ __forceinline__ float fdot2f(h2 a, h2 b, float c) {
    return __builtin_amdgcn_fdot2(a, b, c, false);
}

__device__ __forceinline__ float EXP2F(float x) {
#if __has_builtin(__builtin_amdgcn_exp2f)
    return __builtin_amdgcn_exp2f(x);
#else
    return __expf(x * 0.69314718055994531f);
#endif
}

// value from lane^1 (quad_perm [1,0,3,2]) — pure VALU, no LDS pipe
__device__ __forceinline__ float qswap(float x) {
#if __has_builtin(__builtin_amdgcn_mov_dpp)
    return __int_as_float(
        __builtin_amdgcn_mov_dpp(__float_as_int(x), 0xB1, 0xF, 0xF, true));
#else
    return __shfl_xor(x, 1, 64);
#endif
}

__device__ __forceinline__ h2 as_h2(unsigned int x) {
    return __builtin_bit_cast(h2, x);
}

// pack two f32 -> h2 with one v_cvt_pkrtz_f16_f32
__device__ __forceinline__ h2 pk2(float a, float b) {
#if __has_builtin(__builtin_amdgcn_cvt_pkrtz)
    return __builtin_bit_cast(h2, __builtin_amdgcn_cvt_pkrtz(a, b));
#else
    h2 r; r[0] = (_Float16)a; r[1] = (_Float16)b; return r;
#endif
}

__device__ __forceinline__ unsigned int pku(float a, float b) {
    return __builtin_bit_cast(unsigned int, pk2(a, b));
}

__global__ __launch_bounds__(NTHR, 4)
void meanshift_kernel(const float* __restrict__ E,
                      const float* __restrict__ lbw,
                      float* __restrict__ out)
{
    __shared__ u4v  tile[4 * PSTR];      // 32.1 KB (fp16, 8ch / 16B word)
    __shared__ float sqv[THs * RSTR];    // -0.5*NC*|p|^2, same indexing

    const int bz  = blockIdx.z;
    const int oh  = blockIdx.y * BH - PADp;    // staged row 0 = rel -2
    const int owc = blockIdx.x * BW;           // true tile col origin
    const int gw0 = owc - 4;                   // staged col 0 = rel -4
    const int tid = threadIdx.x;
    const int half = tid & 1;
    const int pix  = tid >> 1;
    const int px   = pix & (BW - 1);
    const int py   = pix >> 4;
    const int c0   = 2 * half;

    const float bwv = log1pf(__expf(lbw[0]));     // softplus
    const float cc2 = 1.0f / (2.0f * bwv * bwv);
    const float NCf = cc2 * 1.44269504f;          // w = 2^(-NC*dist^2)
    const float A2f = 2.0f * NCf;                 // coef on p.z
    const float MZC = -1.0f / (8.0f * NCf);       // mzz = MZC * |zs|^2_full

    const float* Eb = E + (size_t)bz * Dch * HWp;

    // ---- vectorized staging: 1 job/thread = 8ch x 4px ----
    if (tid < NJOB) {
        const int cc  = tid / (THs * 6);
        const int rem = tid - cc * (THs * 6);
        const int row = rem / 6;
        const int g   = rem - row * 6;
        const int gh  = oh + row;
        const int gwb = gw0 + 4 * g;

        float4 F0 = {0.f,0.f,0.f,0.f}, F1 = F0, F2 = F0, F3 = F0;
        float4 F4 = F0, F5 = F0, F6 = F0, F7 = F0;
        if ((unsigned)gh < (unsigned)HH) {
            const float* base = Eb + (size_t)(8 * cc) * HWp + gh * WW;
            if (gwb >= 0 && gwb + 4 <= WW) {      // aligned fast path
                F0 = *(const float4*)(base + 0 * (size_t)HWp + gwb);
                F1 = *(const float4*)(base + 1 * (size_t)HWp + gwb);
                F2 = *(const float4*)(base + 2 * (size_t)HWp + gwb);
                F3 = *(const float4*)(base + 3 * (size_t)HWp + gwb);
                F4 = *(const float4*)(base + 4 * (size_t)HWp + gwb);
                F5 = *(const float4*)(base + 5 * (size_t)HWp + gwb);
                F6 = *(const float4*)(base + 6 * (size_t)HWp + gwb);
                F7 = *(const float4*)(base + 7 * (size_t)HWp + gwb);
            } else {                               // edge: per-element
                const bool i0 = (unsigned)(gwb + 0) < (unsigned)WW;
                const bool i1 = (unsigned)(gwb + 1) < (unsigned)WW;
                const bool i2 = (unsigned)(gwb + 2) < (unsigned)WW;
                const bool i3 = (unsigned)(gwb + 3) < (unsigned)WW;
#define GE(K) F##K = make_float4( \
                    i0 ? base[(K) * (size_t)HWp + gwb + 0] : 0.f, \
                    i1 ? base[(K) * (size_t)HWp + gwb + 1] : 0.f, \
                    i2 ? base[(K) * (size_t)HWp + gwb + 2] : 0.f, \
                    i3 ? base[(K) * (size_t)HWp + gwb + 3] : 0.f)
                GE(0); GE(1); GE(2); GE(3); GE(4); GE(5); GE(6); GE(7);
#undef GE
            }
        }
        // register transpose: 4 pixels' 8-channel words
        const int wbase = cc * PSTR + row * RSTR + 4 * g;
        u4v W;
        W[0]=pku(F0.x,F1.x); W[1]=pku(F2.x,F3.x); W[2]=pku(F4.x,F5.x); W[3]=pku(F6.x,F7.x);
        tile[wbase + 0] = W;
        W[0]=pku(F0.y,F1.y); W[1]=pku(F2.y,F3.y); W[2]=pku(F4.y,F5.y); W[3]=pku(F6.y,F7.y);
        tile[wbase + 1] = W;
        W[0]=pku(F0.z,F1.z); W[1]=pku(F2.z,F3.z); W[2]=pku(F4.z,F5.z); W[3]=pku(F6.z,F7.z);
        tile[wbase + 2] = W;
        W[0]=pku(F0.w,F1.w); W[1]=pku(F2.w,F3.w); W[2]=pku(F4.w,F5.w); W[3]=pku(F6.w,F7.w);
        tile[wbase + 3] = W;
    }
    __syncthreads();

    // ---- precompute sqv = -0.5*NC*|p|^2 (all 32 ch), 1 pixel/thread ----
    if (tid < THs * 24) {
        const int row = tid / 24;
        const int col = tid - row * 24;
        const int p   = row * RSTR + col;
        const u4v t0 = tile[0 * PSTR + p], t1 = tile[1 * PSTR + p];
        const u4v t2 = tile[2 * PSTR + p], t3 = tile[3 * PSTR + p];
        float a0 = 0.f, a1 = 0.f, a2 = 0.f, a3 = 0.f;
        #pragma unroll
        for (int j = 0; j < 4; ++j) {
            const h2 q0 = as_h2(t0[j]); a0 = fdot2f(q0, q0, a0);
            const h2 q1 = as_h2(t1[j]); a1 = fdot2f(q1, q1, a1);
            const h2 q2 = as_h2(t2[j]); a2 = fdot2f(q2, q2, a2);
            const h2 q3 = as_h2(t3[j]); a3 = fdot2f(q3, q3, a3);
        }
        sqv[p] = -0.5f * NCf * ((a0 + a1) + (a2 + a3));
    }
    __syncthreads();

    const u4v* __restrict__ tA = tile + c0 * PSTR;
    const u4v* __restrict__ tB = tA + PSTR;

    // ---- init zs = A2 * z(own pixel), my 16 channels ----
    h2 zs0, zs1, zs2, zs3, zs4, zs5, zs6, zs7;
    {
        const int myp = (py + 2) * RSTR + (px + 4);   // center (rel col px)
        const u4v ca = tA[myp];
        const u4v cb = tB[myp];
        const h2 A2v = pk2(A2f, A2f);
        zs0 = as_h2(ca[0]) * A2v; zs1 = as_h2(ca[1]) * A2v;
        zs2 = as_h2(ca[2]) * A2v; zs3 = as_h2(ca[3]) * A2v;
        zs4 = as_h2(cb[0]) * A2v; zs5 = as_h2(cb[1]) * A2v;
        zs6 = as_h2(cb[2]) * A2v; zs7 = as_h2(cb[3]) * A2v;
    }

    float* Ob = out + (size_t)bz * Dch * HWp;
    const int off    = (oh + PADp + py) * WW + (owc + px);
    const int chbase = 16 * half;

#define NBODY(NPI) do {                                                       \
        const u4v a  = tA[(NPI)];                                             \
        const u4v bq = tB[(NPI)];                                             \
        const float Sv = sqv[(NPI)];                                          \
        const h2 pa0 = as_h2(a[0]),  pa1 = as_h2(a[1]);                       \
        const h2 pa2 = as_h2(a[2]),  pa3 = as_h2(a[3]);                       \
        const h2 pb0 = as_h2(bq[0]), pb1 = as_h2(bq[1]);                      \
        const h2 pb2 = as_h2(bq[2]), pb3 = as_h2(bq[3]);                      \
        float s0 = fdot2f(pa0, zs0, Sv);                                      \
        s0 = fdot2f(pa1, zs1, s0); s0 = fdot2f(pa2, zs2, s0);                 \
        s0 = fdot2f(pa3, zs3, s0);                                            \
        float s1 = fdot2f(pb0, zs4, mzz);                                     \
        s1 = fdot2f(pb1, zs5, s1); s1 = fdot2f(pb2, zs6, s1);                 \
        s1 = fdot2f(pb3, zs7, s1);                                            \
        const float dp  = s0 + s1;                                            \
        const float arg = dp + qswap(dp);   /* A2 p.z - NC|p|^2 - NC|z|^2 */  \
        const float w   = EXP2F(arg);       /* <= ~1 */                       \
        den += w;                                                             \
        const h2 w2v = pk2(w, w);                                             \
        n0 += pa0 * w2v; n1 += pa1 * w2v; n2 += pa2 * w2v; n3 += pa3 * w2v;   \
        n4 += pb0 * w2v; n5 += pb1 * w2v; n6 += pb2 * w2v; n7 += pb3 * w2v;   \
    } while (0)

    #pragma unroll 1
    for (int it = 0; it < ITERS; ++it) {
        // mzz = -0.5*NC*|z|^2 (full 32 ch), from |zs|^2 = A2^2 |z|^2
        float mzz;
        {
            float q0 = fdot2f(zs0, zs0, 0.f);
            q0 = fdot2f(zs1, zs1, q0); q0 = fdot2f(zs2, zs2, q0);
            q0 = fdot2f(zs3, zs3, q0);
            float q1 = fdot2f(zs4, zs4, 0.f);
            q1 = fdot2f(zs5, zs5, q1); q1 = fdot2f(zs6, zs6, q1);
            q1 = fdot2f(zs7, zs7, q1);
            const float qs = q0 + q1;
            mzz = (qs + qswap(qs)) * MZC;
        }

        h2 n0 = {(_Float16)0.f, (_Float16)0.f};
        h2 n1 = n0, n2 = n0, n3 = n0, n4 = n0, n5 = n0, n6 = n0, n7 = n0;
        float den = 0.f;

        #pragma unroll 1
        for (int di = 0; di < 5; ++di) {
            const int rb = (py + di) * RSTR + px + 2;   // rel cols px-2..px+2
            NBODY(rb + 0);
            NBODY(rb + 1);
            NBODY(rb + 2);
            NBODY(rb + 3);
            NBODY(rb + 4);
        }

        const float invf = 1.0f / (den + 1e-6f);
        if (it == ITERS - 1) {
#define WR(IDX, NV, EL) Ob[(size_t)(chbase + (IDX)) * HWp + off] = (float)NV[EL] * invf
            WR(0,  n0, 0); WR(1,  n0, 1); WR(2,  n1, 0); WR(3,  n1, 1);
            WR(4,  n2, 0); WR(5,  n2, 1); WR(6,  n3, 0); WR(7,  n3, 1);
            WR(8,  n4, 0); WR(9,  n4, 1); WR(10, n5, 0); WR(11, n5, 1);
            WR(12, n6, 0); WR(13, n6, 1); WR(14, n7, 0); WR(15, n7, 1);
#undef WR
        } else {
            // zs_new = A2 * (num * invf): fold A2 into the inverse
            const float ia = invf * A2f;
            const h2 iv = pk2(ia, ia);
            zs0 = n0 * iv; zs1 = n1 * iv; zs2 = n2 * iv; zs3 = n3 * iv;
            zs4 = n4 * iv; zs5 = n5 * iv; zs6 = n6 * iv; zs7 = n7 * iv;
        }
    }
#undef NBODY
}

extern "C" void kernel_launch(void* const* d_in, const int* in_sizes, int n_in,
                              void* d_out, int out_size, void* d_ws, size_t ws_size,
                              hipStream_t stream) {
    const float* E   = (const float*)d_in[0];
    const float* lbw = (const float*)d_in[1];
    float* out       = (float*)d_out;

    const int B = in_sizes[0] / (Dch * HWp);       // = 2
    dim3 grid(WW / BW, HH / BH, B);                // (16,16,2) = 512 blocks
    dim3 block(NTHR, 1, 1);                        // 512 threads (2/pixel)
    hipLaunchKernelGGL(meanshift_kernel, grid, block, 0, stream, E, lbw, out);
}